// Round 12
// baseline (590.681 us; speedup 1.0000x reference)
//
#include <hip/hip_runtime.h>

// GraphRec forward, MI355X. Round 12: r10 fscore (non-pipelined, VGPR 76)
// + r11 agg8 (8-lane/dst, edge prefetch) + larger grid for TLP. In/out f32.

typedef unsigned int   u32;
typedef unsigned short u16;
typedef short bf16x8 __attribute__((ext_vector_type(8)));
typedef float f32x4  __attribute__((ext_vector_type(4)));

#define U_N   100000
#define I_N   50000
#define EUI_E 1000000
#define EUU_E 500000
#define DOUT_ROWS 300000
#define RANGE 256      // dsts per bucket
#define PB    256      // partition blocks

// ---------- helpers ----------
__device__ __forceinline__ float bflo(u32 u){ return __uint_as_float(u << 16); }
__device__ __forceinline__ float bfhi(u32 u){ return __uint_as_float(u & 0xffff0000u); }
__device__ __forceinline__ u16 f2bf(float f){
  u32 x = __float_as_uint(f);
  x += 0x7fffu + ((x >> 16) & 1u);
  return (u16)(x >> 16);
}
__device__ __forceinline__ u32 pk2(float a, float b){
  return (u32)f2bf(a) | ((u32)f2bf(b) << 16);
}
__device__ __forceinline__ float actf(float x, float s){ return fmaxf(x, x * s); }
__device__ __forceinline__ void cvt8(uint4 q, float f[8]){
  f[0]=bflo(q.x); f[1]=bfhi(q.x); f[2]=bflo(q.y); f[3]=bfhi(q.y);
  f[4]=bflo(q.z); f[5]=bfhi(q.z); f[6]=bflo(q.w); f[7]=bfhi(q.w);
}

// ---------- MFMA fragment helpers (16x16x32 bf16) ----------
// A: lane l holds row (l&15), k = 8*(l>>4)+j. B: col (l&15), k = 8*(l>>4)+j.
// D: col (l&15), row = 4*(l>>4)+reg  [validated on HW rounds 4-11].
__device__ __forceinline__ bf16x8 bfrag(const float* __restrict__ W, int kt, int nt, int l){
  int c = l & 15, g = l >> 4;
  const float* p = W + (size_t)(kt*32 + g*8) * 64 + nt*16 + c;
  bf16x8 r;
  #pragma unroll
  for (int j = 0; j < 8; ++j) r[j] = (short)f2bf(p[(size_t)j * 64]);
  return r;
}
__device__ __forceinline__ bf16x8 afrag_f32(const float* p){
  float4 a = *(const float4*)p, b = *(const float4*)(p + 4);
  bf16x8 r;
  r[0]=(short)f2bf(a.x); r[1]=(short)f2bf(a.y); r[2]=(short)f2bf(a.z); r[3]=(short)f2bf(a.w);
  r[4]=(short)f2bf(b.x); r[5]=(short)f2bf(b.y); r[6]=(short)f2bf(b.z); r[7]=(short)f2bf(b.w);
  return r;
}
__device__ __forceinline__ bf16x8 afrag_f32s(const float* p, float s){
  float4 a = *(const float4*)p, b = *(const float4*)(p + 4);
  bf16x8 r;
  r[0]=(short)f2bf(a.x*s); r[1]=(short)f2bf(a.y*s); r[2]=(short)f2bf(a.z*s); r[3]=(short)f2bf(a.w*s);
  r[4]=(short)f2bf(b.x*s); r[5]=(short)f2bf(b.y*s); r[6]=(short)f2bf(b.z*s); r[7]=(short)f2bf(b.w*s);
  return r;
}
#define LDT 68
__device__ __forceinline__ void dwrite(float* lb, const f32x4* acc, float slope, int l){
  int c = l & 15, g = l >> 4;
  #pragma unroll
  for (int nt = 0; nt < 4; ++nt){
    #pragma unroll
    for (int rg = 0; rg < 4; ++rg)
      lb[(4*g + rg)*LDT + nt*16 + c] = actf(acc[nt][rg], slope);
  }
}
__device__ __forceinline__ bf16x8 afrag_lds(const float* lb, int kt, int l){
  int r = l & 15, g = l >> 4;
  return afrag_f32(lb + r*LDT + kt*32 + g*8);
}
__device__ __forceinline__ void store_rows2(const float* lb, u16* lo, u16* hi, int ndout,
                                            int base, int nrows, int l){
  int r = l >> 2, q = l & 3;
  if (r >= nrows) return;
  int row = base + r;
  u16* out = (row < ndout) ? lo + (size_t)row * 64 : hi + (size_t)(row - ndout) * 64;
  const float* src = lb + r*LDT + q*16;
  float4 a = *(const float4*)src, b = *(const float4*)(src+4);
  float4 c = *(const float4*)(src+8), d = *(const float4*)(src+12);
  uint4 w0, w1;
  w0.x = pk2(a.x,a.y); w0.y = pk2(a.z,a.w); w0.z = pk2(b.x,b.y); w0.w = pk2(b.z,b.w);
  w1.x = pk2(c.x,c.y); w1.y = pk2(c.z,c.w); w1.z = pk2(d.x,d.y); w1.w = pk2(d.z,d.w);
  u32* dst = (u32*)(out + (size_t)q*16);
  *(uint4*)dst = w0;
  *(uint4*)(dst + 4) = w1;
}
__device__ __forceinline__ void store_rows_f32(const float* lb, float* out,
                                               int base, int nrows, int l){
  int r = l >> 2, q = l & 3;
  if (r >= nrows) return;
  const float* src = lb + r*LDT + q*16;
  float* dst = out + (size_t)(base + r)*64 + q*16;
  *(float4*)(dst)    = *(const float4*)(src);
  *(float4*)(dst+4)  = *(const float4*)(src+4);
  *(float4*)(dst+8)  = *(const float4*)(src+8);
  *(float4*)(dst+12) = *(const float4*)(src+12);
}
#define MFMA(a,b,c) __builtin_amdgcn_mfma_f32_16x16x32_bf16((a),(b),(c),0,0,0)

// ---------- pair-table value MLP ----------
__global__ void __launch_bounds__(256) mfma_pair_k(
    const float* __restrict__ embA, const float* __restrict__ embR,
    const float* __restrict__ W1, const float* __restrict__ b1,
    const float* __restrict__ W2, const float* __restrict__ b2,
    float slope, int plo, int phi, u16* __restrict__ Xlo, u16* __restrict__ Xhi, int ndout)
{
  __shared__ float lbuf[4][16*LDT];
  int l   = threadIdx.x & 63;
  int wid = threadIdx.x >> 6;
  float* lb = lbuf[wid];
  int c = l & 15;
  bf16x8 w1f[4][4], w2f[2][4];
  #pragma unroll
  for (int kt = 0; kt < 4; ++kt)
    #pragma unroll
    for (int nt = 0; nt < 4; ++nt) w1f[kt][nt] = bfrag(W1, kt, nt, l);
  #pragma unroll
  for (int kt = 0; kt < 2; ++kt)
    #pragma unroll
    for (int nt = 0; nt < 4; ++nt) w2f[kt][nt] = bfrag(W2, kt, nt, l);
  float bias1[4], bias2[4];
  #pragma unroll
  for (int nt = 0; nt < 4; ++nt){ bias1[nt] = b1[nt*16 + c]; bias2[nt] = b2[nt*16 + c]; }

  int n = phi - plo;
  int ngrp = (n + 15) >> 4;
  for (int grp = blockIdx.x*4 + wid; grp < ngrp; grp += gridDim.x*4){
    int base = grp * 16;
    int p = plo + base + (l & 15);
    if (p >= phi) p = phi - 1;
    int i = p / 5, r = p - 5*i;
    const float* ra = embA + (size_t)i * 64;
    const float* rr = embR + (size_t)r * 64;
    bf16x8 a0 = afrag_f32(ra + (l>>4)*8);
    bf16x8 a1 = afrag_f32(ra + 32 + (l>>4)*8);
    bf16x8 a2 = afrag_f32(rr + (l>>4)*8);
    bf16x8 a3 = afrag_f32(rr + 32 + (l>>4)*8);
    f32x4 acc[4];
    #pragma unroll
    for (int nt = 0; nt < 4; ++nt){
      f32x4 v; v[0]=bias1[nt]; v[1]=bias1[nt]; v[2]=bias1[nt]; v[3]=bias1[nt];
      v = MFMA(a0, w1f[0][nt], v);
      v = MFMA(a1, w1f[1][nt], v);
      v = MFMA(a2, w1f[2][nt], v);
      v = MFMA(a3, w1f[3][nt], v);
      acc[nt] = v;
    }
    dwrite(lb, acc, slope, l);
    bf16x8 x0 = afrag_lds(lb, 0, l);
    bf16x8 x1 = afrag_lds(lb, 1, l);
    #pragma unroll
    for (int nt = 0; nt < 4; ++nt){
      f32x4 v; v[0]=bias2[nt]; v[1]=bias2[nt]; v[2]=bias2[nt]; v[3]=bias2[nt];
      v = MFMA(x0, w2f[0][nt], v);
      v = MFMA(x1, w2f[1][nt], v);
      acc[nt] = v;
    }
    dwrite(lb, acc, slope, l);
    int nrows = n - base; if (nrows > 16) nrows = 16;
    store_rows2(lb, Xlo, Xhi, ndout, base, nrows, l);
  }
}

// ---------- single linear ----------
template<int AF32>
__global__ void __launch_bounds__(256) mfma_lin_k(
    const void* __restrict__ A, const float* __restrict__ W, const float* __restrict__ b,
    int has_bias, u16* __restrict__ out, int N)
{
  __shared__ float lbuf[4][16*LDT];
  int l   = threadIdx.x & 63;
  int wid = threadIdx.x >> 6;
  float* lb = lbuf[wid];
  int c = l & 15;
  bf16x8 wf[2][4];
  #pragma unroll
  for (int kt = 0; kt < 2; ++kt)
    #pragma unroll
    for (int nt = 0; nt < 4; ++nt) wf[kt][nt] = bfrag(W, kt, nt, l);
  float bias[4];
  #pragma unroll
  for (int nt = 0; nt < 4; ++nt) bias[nt] = has_bias ? b[nt*16 + c] : 0.0f;

  int ngrp = (N + 15) >> 4;
  for (int grp = blockIdx.x*4 + wid; grp < ngrp; grp += gridDim.x*4){
    int base = grp * 16;
    int ar = base + (l & 15);
    if (ar >= N) ar = N - 1;
    bf16x8 a0, a1;
    if (AF32){
      const float* row = (const float*)A + (size_t)ar * 64;
      a0 = afrag_f32(row + (l>>4)*8);
      a1 = afrag_f32(row + 32 + (l>>4)*8);
    } else {
      const u16* row = (const u16*)A + (size_t)ar * 64;
      a0 = *(const bf16x8*)(row + (l>>4)*8);
      a1 = *(const bf16x8*)(row + 32 + (l>>4)*8);
    }
    f32x4 acc[4];
    #pragma unroll
    for (int nt = 0; nt < 4; ++nt){
      f32x4 v; v[0]=bias[nt]; v[1]=bias[nt]; v[2]=bias[nt]; v[3]=bias[nt];
      v = MFMA(a0, wf[0][nt], v);
      v = MFMA(a1, wf[1][nt], v);
      acc[nt] = v;
    }
    dwrite(lb, acc, 1.0f, l);
    int nrows = N - base; if (nrows > 16) nrows = 16;
    store_rows2(lb, out, out, 1<<30, base, nrows, l);
  }
}

// ---------- MFMA finalize ----------
template<int OUTBF>
__global__ void __launch_bounds__(256) mfma_fin_k(
    const float* __restrict__ acc, const float* __restrict__ sdst,
    const float* __restrict__ W, const float* __restrict__ b,
    void* __restrict__ out, int N)
{
  __shared__ float lbuf[4][16*LDT];
  int l   = threadIdx.x & 63;
  int wid = threadIdx.x >> 6;
  float* lb = lbuf[wid];
  int r16 = l & 15, g = l >> 4;
  bf16x8 wf[2][4];
  #pragma unroll
  for (int kt = 0; kt < 2; ++kt)
    #pragma unroll
    for (int nt = 0; nt < 4; ++nt) wf[kt][nt] = bfrag(W, kt, nt, l);
  float bias[4];
  #pragma unroll
  for (int nt = 0; nt < 4; ++nt) bias[nt] = b[nt*16 + r16];

  int ngrp = (N + 15) >> 4;
  for (int grp = blockIdx.x*4 + wid; grp < ngrp; grp += gridDim.x*4){
    int base = grp * 16;
    int ar = base + r16; if (ar >= N) ar = N - 1;
    float s = sdst[ar];
    float inv = (s > 0.f) ? 1.0f / s : 0.0f;
    const float* row = acc + (size_t)ar * 64;
    bf16x8 a0 = afrag_f32s(row + g*8, inv);
    bf16x8 a1 = afrag_f32s(row + 32 + g*8, inv);
    f32x4 o[4];
    #pragma unroll
    for (int nt = 0; nt < 4; ++nt){
      f32x4 v; v[0]=bias[nt]; v[1]=bias[nt]; v[2]=bias[nt]; v[3]=bias[nt];
      v = MFMA(a0, wf[0][nt], v);
      v = MFMA(a1, wf[1][nt], v);
      o[nt] = v;
    }
    dwrite(lb, o, 0.2f, l);
    int nrows = N - base; if (nrows > 16) nrows = 16;
    if (OUTBF) store_rows2(lb, (u16*)out, (u16*)out, 1<<30, base, nrows, l);
    else       store_rows_f32(lb, (float*)out, base, nrows, l);
  }
}

// ---------- MFMA social finalize ----------
__global__ void __launch_bounds__(256) mfma_fin_social_k(
    const float* __restrict__ accS, const float* __restrict__ sdst,
    const u16* __restrict__ hI,
    const float* __restrict__ wS, const float* __restrict__ bS,
    const float* __restrict__ W2, const float* __restrict__ b2,
    float* __restrict__ out, int N)
{
  __shared__ float lbuf[4][16*LDT];
  int l   = threadIdx.x & 63;
  int wid = threadIdx.x >> 6;
  float* lb = lbuf[wid];
  int r16 = l & 15, g = l >> 4;
  bf16x8 wsf[2][4], w2f[4][4];
  #pragma unroll
  for (int kt = 0; kt < 2; ++kt)
    #pragma unroll
    for (int nt = 0; nt < 4; ++nt) wsf[kt][nt] = bfrag(wS, kt, nt, l);
  #pragma unroll
  for (int kt = 0; kt < 4; ++kt)
    #pragma unroll
    for (int nt = 0; nt < 4; ++nt) w2f[kt][nt] = bfrag(W2, kt, nt, l);
  float biasS[4], bias2[4];
  #pragma unroll
  for (int nt = 0; nt < 4; ++nt){ biasS[nt] = bS[nt*16 + r16]; bias2[nt] = b2[nt*16 + r16]; }

  int ngrp = (N + 15) >> 4;
  for (int grp = blockIdx.x*4 + wid; grp < ngrp; grp += gridDim.x*4){
    int base = grp * 16;
    int ar = base + r16; if (ar >= N) ar = N - 1;
    float s = sdst[ar];
    float inv = (s > 0.f) ? 1.0f / s : 0.0f;
    const float* row = accS + (size_t)ar * 64;
    bf16x8 a0 = afrag_f32s(row + g*8, inv);
    bf16x8 a1 = afrag_f32s(row + 32 + g*8, inv);
    f32x4 hs[4];
    #pragma unroll
    for (int nt = 0; nt < 4; ++nt){
      f32x4 v; v[0]=biasS[nt]; v[1]=biasS[nt]; v[2]=biasS[nt]; v[3]=biasS[nt];
      v = MFMA(a0, wsf[0][nt], v);
      v = MFMA(a1, wsf[1][nt], v);
      hs[nt] = v;
    }
    dwrite(lb, hs, 0.2f, l);
    bf16x8 h0 = afrag_lds(lb, 0, l);
    bf16x8 h1 = afrag_lds(lb, 1, l);
    const u16* hrow = hI + (size_t)ar * 64;
    bf16x8 i0 = *(const bf16x8*)(hrow + g*8);
    bf16x8 i1 = *(const bf16x8*)(hrow + 32 + g*8);
    f32x4 o[4];
    #pragma unroll
    for (int nt = 0; nt < 4; ++nt){
      f32x4 v; v[0]=bias2[nt]; v[1]=bias2[nt]; v[2]=bias2[nt]; v[3]=bias2[nt];
      v = MFMA(i0, w2f[0][nt], v);
      v = MFMA(i1, w2f[1][nt], v);
      v = MFMA(h0, w2f[2][nt], v);
      v = MFMA(h1, w2f[3][nt], v);
      o[nt] = v;
    }
    dwrite(lb, o, 0.2f, l);
    int nrows = N - base; if (nrows > 16) nrows = 16;
    store_rows_f32(lb, out, base, nrows, l);
  }
}

// ---------- CSR build: bucket pipeline ----------
__global__ void __launch_bounds__(256) hist2_k(const int* __restrict__ dstI, int E,
                                               int* __restrict__ H, int nb){
  __shared__ int h[512];
  for (int t = threadIdx.x; t < nb; t += 256) h[t] = 0;
  __syncthreads();
  int chunk = (E + PB - 1) / PB;
  int s = blockIdx.x * chunk;
  int e_end = s + chunk; if (e_end > E) e_end = E;
  for (int e = s + threadIdx.x; e < e_end; e += 256)
    atomicAdd(&h[dstI[e] >> 8], 1);
  __syncthreads();
  for (int t = threadIdx.x; t < nb; t += 256) H[t*PB + blockIdx.x] = h[t];
}
__global__ void __launch_bounds__(PB) totB_k(const int* __restrict__ H, int* __restrict__ tot){
  __shared__ int sh[PB];
  int b = blockIdx.x;
  sh[threadIdx.x] = H[b*PB + threadIdx.x];
  __syncthreads();
  for (int o = PB/2; o > 0; o >>= 1){
    if (threadIdx.x < o) sh[threadIdx.x] += sh[threadIdx.x + o];
    __syncthreads();
  }
  if (threadIdx.x == 0) tot[b] = sh[0];
}
__global__ void __launch_bounds__(512) scanB_k(const int* __restrict__ tot,
                                               int* __restrict__ baseB, int nb){
  __shared__ int sh[512];
  int v = (threadIdx.x < nb) ? tot[threadIdx.x] : 0;
  sh[threadIdx.x] = v;
  __syncthreads();
  for (int o = 1; o < 512; o <<= 1){
    int t = (threadIdx.x >= o) ? sh[threadIdx.x - o] : 0;
    __syncthreads();
    sh[threadIdx.x] += t;
    __syncthreads();
  }
  if (threadIdx.x < nb) baseB[threadIdx.x] = sh[threadIdx.x] - v;
  if (threadIdx.x == nb - 1) baseB[nb] = sh[threadIdx.x];
}
__global__ void __launch_bounds__(PB) offB_k(int* __restrict__ H, const int* __restrict__ baseB){
  __shared__ int sh[PB];
  int b = blockIdx.x;
  int v = H[b*PB + threadIdx.x];
  sh[threadIdx.x] = v;
  __syncthreads();
  for (int o = 1; o < PB; o <<= 1){
    int t = (threadIdx.x >= o) ? sh[threadIdx.x - o] : 0;
    __syncthreads();
    sh[threadIdx.x] += t;
    __syncthreads();
  }
  H[b*PB + threadIdx.x] = baseB[b] + sh[threadIdx.x] - v;
}
__global__ void __launch_bounds__(256) part_k(
    const int* __restrict__ keyI, const int* __restrict__ ratI, int kmul,
    const int* __restrict__ dstI, const int* __restrict__ H, int nb,
    long long* __restrict__ kd2, int E){
  __shared__ int cur[512];
  for (int t = threadIdx.x; t < nb; t += 256) cur[t] = H[t*PB + blockIdx.x];
  __syncthreads();
  int chunk = (E + PB - 1) / PB;
  int s = blockIdx.x * chunk;
  int e_end = s + chunk; if (e_end > E) e_end = E;
  for (int e = s + threadIdx.x; e < e_end; e += 256){
    int d = dstI[e];
    int key = keyI[e]*kmul + (ratI ? ratI[e] : 0);
    int pos = atomicAdd(&cur[d >> 8], 1);
    long long v = ((long long)d << 32) | (unsigned)key;
    __builtin_nontemporal_store(v, kd2 + pos);
  }
}
__global__ void __launch_bounds__(256) bsort_k(
    const long long* __restrict__ kd2, const int* __restrict__ baseB,
    int N, long long* __restrict__ kd, int* __restrict__ rowptr, int E){
  __shared__ int cnt[RANGE];
  __shared__ int off[RANGE];
  int b = blockIdx.x;
  int lo = baseB[b], hi = baseB[b+1];
  cnt[threadIdx.x] = 0;
  __syncthreads();
  for (int k = lo + (int)threadIdx.x; k < hi; k += 256){
    int d = (int)(kd2[k] >> 32);
    atomicAdd(&cnt[d & 255], 1);
  }
  __syncthreads();
  int v = cnt[threadIdx.x];
  off[threadIdx.x] = v;
  __syncthreads();
  for (int o = 1; o < RANGE; o <<= 1){
    int t = (threadIdx.x >= o) ? off[threadIdx.x - o] : 0;
    __syncthreads();
    off[threadIdx.x] += t;
    __syncthreads();
  }
  int excl = off[threadIdx.x] - v;
  int d0 = b*RANGE + (int)threadIdx.x;
  if (d0 < N) rowptr[d0] = lo + excl;
  if (b == (int)gridDim.x - 1 && threadIdx.x == 0) rowptr[N] = E;
  __syncthreads();
  cnt[threadIdx.x] = lo + excl;
  __syncthreads();
  for (int k = lo + (int)threadIdx.x; k < hi; k += 256){
    long long v2 = kd2[k];
    int d = (int)(v2 >> 32);
    int pos = atomicAdd(&cnt[d & 255], 1);
    kd[pos] = v2;
  }
}

// ---------- fused MFMA score over sorted edges (r10 non-pipelined body) ----------
template<int CY>
__global__ void __launch_bounds__(256) fscore_k(
    const int2* __restrict__ kd,
    const u16* __restrict__ Xlo, const u16* __restrict__ Xhi, int ndout,
    int klo, int nk,
    const u16* __restrict__ Dtab,
    const float* __restrict__ Wy,
    const float* __restrict__ W2, const float* __restrict__ b2,
    const float* __restrict__ w3, const float* __restrict__ b3,
    float* __restrict__ esc, int E)
{
  __shared__ float lbuf[CY ? 4*16*LDT : 4];
  int l   = threadIdx.x & 63;
  int wid = threadIdx.x >> 6;
  int r16 = l & 15, g = l >> 4;
  float* lb = lbuf + (CY ? wid*16*LDT : 0);
  bf16x8 wyf[2][4], w2f[2][4];
  if (CY){
    #pragma unroll
    for (int kt = 0; kt < 2; ++kt)
      #pragma unroll
      for (int nt = 0; nt < 4; ++nt) wyf[kt][nt] = bfrag(Wy, kt, nt, l);
  }
  #pragma unroll
  for (int kt = 0; kt < 2; ++kt)
    #pragma unroll
    for (int nt = 0; nt < 4; ++nt) w2f[kt][nt] = bfrag(W2, kt, nt, l);
  f32x4 b2v[4]; float w3v[4];
  #pragma unroll
  for (int nt = 0; nt < 4; ++nt){
    float bv = b2[nt*16 + r16];
    f32x4 t; t[0]=bv; t[1]=bv; t[2]=bv; t[3]=bv;
    b2v[nt] = t;
    w3v[nt] = w3[nt*16 + r16];
  }
  float b3v = b3[0];

  int ngrp = (E + 15) >> 4;
  for (int grp = blockIdx.x*4 + wid; grp < ngrp; grp += gridDim.x*4){
    int pos = grp*16 + r16;
    int pc  = pos < E ? pos : E - 1;
    int2 kde = kd[pc];
    int j   = kde.x - klo;
    bool inr = (pos < E) && ((unsigned)j < (unsigned)nk);
    unsigned long long bal = __ballot(inr ? 1 : 0);
    uint4 xa = {0,0,0,0}, xb = xa, da = xa, db = xa;
    if (inr){
      const u16* xr = (j < ndout) ? Xlo + (size_t)j * 64 : Xhi + (size_t)(j - ndout) * 64;
      xa = *(const uint4*)(xr + g*8);
      xb = *(const uint4*)(xr + 32 + g*8);
      const u16* dr = Dtab + (size_t)kde.y * 64;
      da = *(const uint4*)(dr + g*8);
      db = *(const uint4*)(dr + 32 + g*8);
    }
    bf16x8 p0, p1;
    float dfa[8], dfb[8];
    cvt8(da, dfa); cvt8(db, dfb);
    if (CY){
      bf16x8 a0 = *reinterpret_cast<const bf16x8*>(&xa);
      bf16x8 a1 = *reinterpret_cast<const bf16x8*>(&xb);
      f32x4 y[4];
      #pragma unroll
      for (int nt = 0; nt < 4; ++nt){
        f32x4 z; z[0]=0.f; z[1]=0.f; z[2]=0.f; z[3]=0.f;
        z = MFMA(a0, wyf[0][nt], z);
        z = MFMA(a1, wyf[1][nt], z);
        y[nt] = z;
      }
      #pragma unroll
      for (int nt = 0; nt < 4; ++nt)
        #pragma unroll
        for (int rg = 0; rg < 4; ++rg)
          lb[(4*g + rg)*LDT + nt*16 + r16] = y[nt][rg];
      const float* pr = lb + r16*LDT;
      float4 f0 = *(const float4*)(pr + g*8);
      float4 f1 = *(const float4*)(pr + g*8 + 4);
      float4 f2 = *(const float4*)(pr + 32 + g*8);
      float4 f3 = *(const float4*)(pr + 36 + g*8);
      float q0[8] = {f0.x,f0.y,f0.z,f0.w,f1.x,f1.y,f1.z,f1.w};
      float q1[8] = {f2.x,f2.y,f2.z,f2.w,f3.x,f3.y,f3.z,f3.w};
      #pragma unroll
      for (int u = 0; u < 8; ++u){
        p0[u] = (short)f2bf(fmaxf(q0[u] + dfa[u], 0.0f));
        p1[u] = (short)f2bf(fmaxf(q1[u] + dfb[u], 0.0f));
      }
    } else {
      float xfa[8], xfb[8];
      cvt8(xa, xfa); cvt8(xb, xfb);
      #pragma unroll
      for (int u = 0; u < 8; ++u){
        p0[u] = (short)f2bf(fmaxf(xfa[u] + dfa[u], 0.0f));
        p1[u] = (short)f2bf(fmaxf(xfb[u] + dfb[u], 0.0f));
      }
    }
    f32x4 o[4];
    #pragma unroll
    for (int nt = 0; nt < 4; ++nt){
      f32x4 v = b2v[nt];
      v = MFMA(p0, w2f[0][nt], v);
      v = MFMA(p1, w2f[1][nt], v);
      o[nt] = v;
    }
    float part[4] = {0.f, 0.f, 0.f, 0.f};
    #pragma unroll
    for (int nt = 0; nt < 4; ++nt)
      #pragma unroll
      for (int rg = 0; rg < 4; ++rg)
        part[rg] += fmaxf(o[nt][rg], 0.0f) * w3v[nt];
    #pragma unroll
    for (int m = 1; m < 16; m <<= 1){
      #pragma unroll
      for (int rg = 0; rg < 4; ++rg) part[rg] += __shfl_xor(part[rg], m);
    }
    if (r16 < 4){
      int eidx = 4*g + r16;
      int p2 = grp*16 + eidx;
      if (p2 < E && ((bal >> eidx) & 1))
        esc[p2] = __expf(part[r16] + b3v);
    }
  }
}

// ---------- 8-lane-per-dst pipelined segmented accumulate + denominator ----------
template<int FIRST>
__global__ void __launch_bounds__(256) agg8_k(
    const int* __restrict__ rowptr, const int2* __restrict__ kd,
    const float* __restrict__ esc,
    const u16* __restrict__ Xlo, const u16* __restrict__ Xhi, int ndout,
    int klo, int nk,
    float* __restrict__ acc, float* __restrict__ sdst, int N)
{
  int t = blockIdx.x*256 + threadIdx.x;
  int d = t >> 3, q = t & 7;
  if (d >= N) return;
  float a[8];
  float* ar = acc + (size_t)d * 64 + q*8;
  float s;
  if (FIRST){
    #pragma unroll
    for (int u = 0; u < 8; ++u) a[u] = 0.0f;
    s = 0.0f;
  } else {
    float4 v0 = *(const float4*)(ar);
    float4 v1 = *(const float4*)(ar + 4);
    a[0]=v0.x; a[1]=v0.y; a[2]=v0.z; a[3]=v0.w;
    a[4]=v1.x; a[5]=v1.y; a[6]=v1.z; a[7]=v1.w;
    s = sdst[d];
  }
  int k0 = rowptr[d], k1 = rowptr[d+1];
  auto xrow = [&](int key)->const u16*{
    return ((key < ndout) ? Xlo + (size_t)key * 64
                          : Xhi + (size_t)(key - ndout) * 64) + q*8;
  };
  if (k0 < k1){
    int key = kd[k0].x - klo;
    bool ok = (unsigned)key < (unsigned)nk;
    float w = ok ? esc[k0] : 0.0f;
    uint4 x = {0,0,0,0};
    if (ok) x = *(const uint4*)xrow(key);
    for (int k = k0 + 1; k < k1; ++k){
      int key2 = kd[k].x - klo;               // prefetch next edge
      bool ok2 = (unsigned)key2 < (unsigned)nk;
      float w2 = ok2 ? esc[k] : 0.0f;
      uint4 x2 = {0,0,0,0};
      if (ok2) x2 = *(const uint4*)xrow(key2);
      s += w;
      float f[8]; cvt8(x, f);
      #pragma unroll
      for (int u = 0; u < 8; ++u) a[u] = fmaf(w, f[u], a[u]);
      x = x2; w = w2;
    }
    s += w;
    float f[8]; cvt8(x, f);
    #pragma unroll
    for (int u = 0; u < 8; ++u) a[u] = fmaf(w, f[u], a[u]);
  }
  *(float4*)(ar)     = make_float4(a[0], a[1], a[2], a[3]);
  *(float4*)(ar + 4) = make_float4(a[4], a[5], a[6], a[7]);
  if (q == 0) sdst[d] = s;
}

extern "C" void kernel_launch(void* const* d_in, const int* in_sizes, int n_in,
                              void* d_out, int out_size, void* d_ws, size_t ws_size,
                              hipStream_t stream) {
  (void)in_sizes; (void)n_in; (void)out_size;
  const float* user_emb   = (const float*)d_in[0];
  const float* item_emb   = (const float*)d_in[1];
  const float* rating_emb = (const float*)d_in[2];
  const float *gv_w1=(const float*)d_in[3],  *gv_b1=(const float*)d_in[4];
  const float *gv_w2=(const float*)d_in[5],  *gv_b2=(const float*)d_in[6];
  const float *aI_w1=(const float*)d_in[7],  *aI_b1=(const float*)d_in[8];
  const float *aI_w2=(const float*)d_in[9],  *aI_b2=(const float*)d_in[10];
  const float *aI_w3=(const float*)d_in[11], *aI_b3=(const float*)d_in[12];
  const float *wI_w =(const float*)d_in[13], *wI_b =(const float*)d_in[14];
  const float *aS_w1=(const float*)d_in[15], *aS_b1=(const float*)d_in[16];
  const float *aS_w2=(const float*)d_in[17], *aS_b2=(const float*)d_in[18];
  const float *aS_w3=(const float*)d_in[19], *aS_b3=(const float*)d_in[20];
  const float *wS_w =(const float*)d_in[21], *wS_b =(const float*)d_in[22];
  const float *W2_w =(const float*)d_in[23], *W2_b =(const float*)d_in[24];
  const float *gu_w1=(const float*)d_in[25], *gu_b1=(const float*)d_in[26];
  const float *gu_w2=(const float*)d_in[27], *gu_b2=(const float*)d_in[28];
  const float *aU_w1=(const float*)d_in[29], *aU_b1=(const float*)d_in[30];
  const float *aU_w2=(const float*)d_in[31], *aU_b2=(const float*)d_in[32];
  const float *aU_w3=(const float*)d_in[33], *aU_b3=(const float*)d_in[34];
  const float *wU_w =(const float*)d_in[35], *wU_b =(const float*)d_in[36];
  const int* user_e    = (const int*)d_in[37];
  const int* item_e    = (const int*)d_in[38];
  const int* rating_e  = (const int*)d_in[39];
  const int* trust_e   = (const int*)d_in[40];
  const int* trustee_e = (const int*)d_in[41];
  float* dout = (float*)d_out;

  char* base = (char*)d_ws;
  size_t cur = 0;
  auto alloc = [&](size_t bytes)->char*{
    char* p = base + cur; cur += (bytes + 255) & ~(size_t)255; return p;
  };
  u16*   hI     = (u16*)  alloc((size_t)U_N * 64 * 2);
  float* esc    = (float*)alloc((size_t)EUI_E * 4);
  float* sdst   = (float*)alloc((size_t)U_N * 4);
  int*   rowptr = (int*)  alloc((size_t)(U_N + 1) * 4);
  int2*  kd     = (int2*) alloc((size_t)EUI_E * 8);
  int*   H      = (int*)  alloc((size_t)512 * PB * 4);
  int*   tot    = (int*)  alloc(512 * 4);
  int*   baseB  = (int*)  alloc(513 * 4);
  float* acc    = (float*)alloc((size_t)U_N * 64 * 4);   // 25.6 MB
  long long* kd2 = (long long*)acc;                      // alias (CSR build time)
  size_t fixed_end = cur;
  if (ws_size < fixed_end + 13100000) return;
  u16* tabD = (u16*)(base + fixed_end);
  u16* tabX = (u16*)(base + fixed_end + 6500352);
  size_t arena = ws_size - fixed_end;
  u16* Xdout = (u16*)d_out;

  auto cdiv = [](int a, int b){ return (a + b - 1) / b; };
  auto buildCSR = [&](const int* keyI, const int* ratI, int kmul,
                      const int* dstIdx, int E, int N){
    int nb = cdiv(N, RANGE);
    hist2_k<<<PB, 256, 0, stream>>>(dstIdx, E, H, nb);
    totB_k<<<nb, PB, 0, stream>>>(H, tot);
    scanB_k<<<1, 512, 0, stream>>>(tot, baseB, nb);
    offB_k<<<nb, PB, 0, stream>>>(H, baseB);
    part_k<<<PB, 256, 0, stream>>>(keyI, ratI, kmul, dstIdx, H, nb, kd2, E);
    bsort_k<<<nb, 256, 0, stream>>>(kd2, baseB, N, (long long*)kd, rowptr, E);
  };
  auto gCap = [&](int groups){ int g = cdiv(groups, 4); return g > 6144 ? 6144 : g; };

  // ============ Phase 1: ItemAgg (dst = user) ============
  {
    buildCSR(item_e, rating_e, 5, user_e, EUI_E, U_N);
    mfma_lin_k<1><<<gCap(cdiv(U_N,16)), 256, 0, stream>>>(user_emb, aI_w1 + 64*64, aI_b1, 1, tabD, U_N);
    const int NK = 250000;
    mfma_pair_k<<<gCap(cdiv(NK,16)), 256, 0, stream>>>(item_emb, rating_emb,
        gv_w1, gv_b1, gv_w2, gv_b2, 0.01f, 0, NK, Xdout, Xdout, 1<<30);
    fscore_k<1><<<gCap(cdiv(EUI_E,16)), 256, 0, stream>>>(kd,
        Xdout, Xdout, 1<<30, 0, NK, tabD, aI_w1, aI_w2, aI_b2, aI_w3, aI_b3, esc, EUI_E);
    agg8_k<1><<<cdiv(U_N*8,256), 256, 0, stream>>>(rowptr, kd, esc,
        Xdout, Xdout, 1<<30, 0, NK, acc, sdst, U_N);
    mfma_fin_k<1><<<gCap(cdiv(U_N,16)), 256, 0, stream>>>(acc, sdst, wI_w, wI_b, hI, U_N);
  }

  // ============ Phase 2: UserAgg (dst = item) ============
  {
    buildCSR(user_e, rating_e, 5, item_e, EUI_E, I_N);
    mfma_lin_k<1><<<gCap(cdiv(I_N,16)), 256, 0, stream>>>(item_emb, aU_w1 + 64*64, aU_b1, 1, tabD, I_N);
    bool single = arena >= 33000000;
    int CP = single ? 500000 : 250000;
    int ND = single ? DOUT_ROWS : (1<<30);
    for (int klo = 0; klo < 500000; klo += CP){
      mfma_pair_k<<<gCap(cdiv(CP,16)), 256, 0, stream>>>(user_emb, rating_emb,
          gu_w1, gu_b1, gu_w2, gu_b2, 0.0f, klo, klo + CP, Xdout, tabX, ND);
      fscore_k<1><<<gCap(cdiv(EUI_E,16)), 256, 0, stream>>>(kd,
          Xdout, tabX, ND, klo, CP, tabD, aU_w1, aU_w2, aU_b2, aU_w3, aU_b3, esc, EUI_E);
      if (klo == 0)
        agg8_k<1><<<cdiv(I_N*8,256), 256, 0, stream>>>(rowptr, kd, esc,
            Xdout, tabX, ND, klo, CP, acc, sdst, I_N);
      else
        agg8_k<0><<<cdiv(I_N*8,256), 256, 0, stream>>>(rowptr, kd, esc,
            Xdout, tabX, ND, klo, CP, acc, sdst, I_N);
    }
    mfma_fin_k<0><<<gCap(cdiv(I_N,16)), 256, 0, stream>>>(acc, sdst, wU_w, wU_b,
        dout + (size_t)U_N * 64, I_N);
  }

  // ============ Phase 3: SocialAgg (dst = trustee) ============
  {
    buildCSR(trust_e, (const int*)nullptr, 1, trustee_e, EUU_E, U_N);
    u16* SD = Xdout;
    mfma_lin_k<1><<<gCap(cdiv(U_N,16)), 256, 0, stream>>>(user_emb, aS_w1, aS_b1, 0, tabD, U_N); // SS
    mfma_lin_k<0><<<gCap(cdiv(U_N,16)), 256, 0, stream>>>(hI, aS_w1 + 64*64, aS_b1, 1, SD, U_N); // SD
    fscore_k<0><<<gCap(cdiv(EUU_E,16)), 256, 0, stream>>>(kd,
        tabD, tabD, 1<<30, 0, U_N, SD, (const float*)nullptr,
        aS_w2, aS_b2, aS_w3, aS_b3, esc, EUU_E);
    agg8_k<1><<<cdiv(U_N*8,256), 256, 0, stream>>>(rowptr, kd, esc,
        hI, hI, 1<<30, 0, U_N, acc, sdst, U_N);
    mfma_fin_social_k<<<gCap(cdiv(U_N,16)), 256, 0, stream>>>(acc, sdst, hI,
        wS_w, wS_b, W2_w, W2_b, dout, U_N);
  }
}

// Round 13
// 501.526 us; speedup vs baseline: 1.1778x; 1.1778x over previous
//
#include <hip/hip_runtime.h>

// GraphRec forward, MI355X. Round 13: r10 config (gCap 1536) + agg8 from r11.
// Banking round. Inputs f32, output f32.

typedef unsigned int   u32;
typedef unsigned short u16;
typedef short bf16x8 __attribute__((ext_vector_type(8)));
typedef float f32x4  __attribute__((ext_vector_type(4)));

#define U_N   100000
#define I_N   50000
#define EUI_E 1000000
#define EUU_E 500000
#define DOUT_ROWS 300000
#define RANGE 256      // dsts per bucket
#define PB    256      // partition blocks

// ---------- helpers ----------
__device__ __forceinline__ float bflo(u32 u){ return __uint_as_float(u << 16); }
__device__ __forceinline__ float bfhi(u32 u){ return __uint_as_float(u & 0xffff0000u); }
__device__ __forceinline__ u16 f2bf(float f){
  u32 x = __float_as_uint(f);
  x += 0x7fffu + ((x >> 16) & 1u);
  return (u16)(x >> 16);
}
__device__ __forceinline__ u32 pk2(float a, float b){
  return (u32)f2bf(a) | ((u32)f2bf(b) << 16);
}
__device__ __forceinline__ float actf(float x, float s){ return fmaxf(x, x * s); }
__device__ __forceinline__ void cvt8(uint4 q, float f[8]){
  f[0]=bflo(q.x); f[1]=bfhi(q.x); f[2]=bflo(q.y); f[3]=bfhi(q.y);
  f[4]=bflo(q.z); f[5]=bfhi(q.z); f[6]=bflo(q.w); f[7]=bfhi(q.w);
}

// ---------- MFMA fragment helpers (16x16x32 bf16) ----------
// A: lane l holds row (l&15), k = 8*(l>>4)+j. B: col (l&15), k = 8*(l>>4)+j.
// D: col (l&15), row = 4*(l>>4)+reg  [validated on HW rounds 4-12].
__device__ __forceinline__ bf16x8 bfrag(const float* __restrict__ W, int kt, int nt, int l){
  int c = l & 15, g = l >> 4;
  const float* p = W + (size_t)(kt*32 + g*8) * 64 + nt*16 + c;
  bf16x8 r;
  #pragma unroll
  for (int j = 0; j < 8; ++j) r[j] = (short)f2bf(p[(size_t)j * 64]);
  return r;
}
__device__ __forceinline__ bf16x8 afrag_f32(const float* p){
  float4 a = *(const float4*)p, b = *(const float4*)(p + 4);
  bf16x8 r;
  r[0]=(short)f2bf(a.x); r[1]=(short)f2bf(a.y); r[2]=(short)f2bf(a.z); r[3]=(short)f2bf(a.w);
  r[4]=(short)f2bf(b.x); r[5]=(short)f2bf(b.y); r[6]=(short)f2bf(b.z); r[7]=(short)f2bf(b.w);
  return r;
}
__device__ __forceinline__ bf16x8 afrag_f32s(const float* p, float s){
  float4 a = *(const float4*)p, b = *(const float4*)(p + 4);
  bf16x8 r;
  r[0]=(short)f2bf(a.x*s); r[1]=(short)f2bf(a.y*s); r[2]=(short)f2bf(a.z*s); r[3]=(short)f2bf(a.w*s);
  r[4]=(short)f2bf(b.x*s); r[5]=(short)f2bf(b.y*s); r[6]=(short)f2bf(b.z*s); r[7]=(short)f2bf(b.w*s);
  return r;
}
#define LDT 68
__device__ __forceinline__ void dwrite(float* lb, const f32x4* acc, float slope, int l){
  int c = l & 15, g = l >> 4;
  #pragma unroll
  for (int nt = 0; nt < 4; ++nt){
    #pragma unroll
    for (int rg = 0; rg < 4; ++rg)
      lb[(4*g + rg)*LDT + nt*16 + c] = actf(acc[nt][rg], slope);
  }
}
__device__ __forceinline__ bf16x8 afrag_lds(const float* lb, int kt, int l){
  int r = l & 15, g = l >> 4;
  return afrag_f32(lb + r*LDT + kt*32 + g*8);
}
__device__ __forceinline__ void store_rows2(const float* lb, u16* lo, u16* hi, int ndout,
                                            int base, int nrows, int l){
  int r = l >> 2, q = l & 3;
  if (r >= nrows) return;
  int row = base + r;
  u16* out = (row < ndout) ? lo + (size_t)row * 64 : hi + (size_t)(row - ndout) * 64;
  const float* src = lb + r*LDT + q*16;
  float4 a = *(const float4*)src, b = *(const float4*)(src+4);
  float4 c = *(const float4*)(src+8), d = *(const float4*)(src+12);
  uint4 w0, w1;
  w0.x = pk2(a.x,a.y); w0.y = pk2(a.z,a.w); w0.z = pk2(b.x,b.y); w0.w = pk2(b.z,b.w);
  w1.x = pk2(c.x,c.y); w1.y = pk2(c.z,c.w); w1.z = pk2(d.x,d.y); w1.w = pk2(d.z,d.w);
  u32* dst = (u32*)(out + (size_t)q*16);
  *(uint4*)dst = w0;
  *(uint4*)(dst + 4) = w1;
}
__device__ __forceinline__ void store_rows_f32(const float* lb, float* out,
                                               int base, int nrows, int l){
  int r = l >> 2, q = l & 3;
  if (r >= nrows) return;
  const float* src = lb + r*LDT + q*16;
  float* dst = out + (size_t)(base + r)*64 + q*16;
  *(float4*)(dst)    = *(const float4*)(src);
  *(float4*)(dst+4)  = *(const float4*)(src+4);
  *(float4*)(dst+8)  = *(const float4*)(src+8);
  *(float4*)(dst+12) = *(const float4*)(src+12);
}
#define MFMA(a,b,c) __builtin_amdgcn_mfma_f32_16x16x32_bf16((a),(b),(c),0,0,0)

// ---------- pair-table value MLP ----------
__global__ void __launch_bounds__(256) mfma_pair_k(
    const float* __restrict__ embA, const float* __restrict__ embR,
    const float* __restrict__ W1, const float* __restrict__ b1,
    const float* __restrict__ W2, const float* __restrict__ b2,
    float slope, int plo, int phi, u16* __restrict__ Xlo, u16* __restrict__ Xhi, int ndout)
{
  __shared__ float lbuf[4][16*LDT];
  int l   = threadIdx.x & 63;
  int wid = threadIdx.x >> 6;
  float* lb = lbuf[wid];
  int c = l & 15;
  bf16x8 w1f[4][4], w2f[2][4];
  #pragma unroll
  for (int kt = 0; kt < 4; ++kt)
    #pragma unroll
    for (int nt = 0; nt < 4; ++nt) w1f[kt][nt] = bfrag(W1, kt, nt, l);
  #pragma unroll
  for (int kt = 0; kt < 2; ++kt)
    #pragma unroll
    for (int nt = 0; nt < 4; ++nt) w2f[kt][nt] = bfrag(W2, kt, nt, l);
  float bias1[4], bias2[4];
  #pragma unroll
  for (int nt = 0; nt < 4; ++nt){ bias1[nt] = b1[nt*16 + c]; bias2[nt] = b2[nt*16 + c]; }

  int n = phi - plo;
  int ngrp = (n + 15) >> 4;
  for (int grp = blockIdx.x*4 + wid; grp < ngrp; grp += gridDim.x*4){
    int base = grp * 16;
    int p = plo + base + (l & 15);
    if (p >= phi) p = phi - 1;
    int i = p / 5, r = p - 5*i;
    const float* ra = embA + (size_t)i * 64;
    const float* rr = embR + (size_t)r * 64;
    bf16x8 a0 = afrag_f32(ra + (l>>4)*8);
    bf16x8 a1 = afrag_f32(ra + 32 + (l>>4)*8);
    bf16x8 a2 = afrag_f32(rr + (l>>4)*8);
    bf16x8 a3 = afrag_f32(rr + 32 + (l>>4)*8);
    f32x4 acc[4];
    #pragma unroll
    for (int nt = 0; nt < 4; ++nt){
      f32x4 v; v[0]=bias1[nt]; v[1]=bias1[nt]; v[2]=bias1[nt]; v[3]=bias1[nt];
      v = MFMA(a0, w1f[0][nt], v);
      v = MFMA(a1, w1f[1][nt], v);
      v = MFMA(a2, w1f[2][nt], v);
      v = MFMA(a3, w1f[3][nt], v);
      acc[nt] = v;
    }
    dwrite(lb, acc, slope, l);
    bf16x8 x0 = afrag_lds(lb, 0, l);
    bf16x8 x1 = afrag_lds(lb, 1, l);
    #pragma unroll
    for (int nt = 0; nt < 4; ++nt){
      f32x4 v; v[0]=bias2[nt]; v[1]=bias2[nt]; v[2]=bias2[nt]; v[3]=bias2[nt];
      v = MFMA(x0, w2f[0][nt], v);
      v = MFMA(x1, w2f[1][nt], v);
      acc[nt] = v;
    }
    dwrite(lb, acc, slope, l);
    int nrows = n - base; if (nrows > 16) nrows = 16;
    store_rows2(lb, Xlo, Xhi, ndout, base, nrows, l);
  }
}

// ---------- single linear ----------
template<int AF32>
__global__ void __launch_bounds__(256) mfma_lin_k(
    const void* __restrict__ A, const float* __restrict__ W, const float* __restrict__ b,
    int has_bias, u16* __restrict__ out, int N)
{
  __shared__ float lbuf[4][16*LDT];
  int l   = threadIdx.x & 63;
  int wid = threadIdx.x >> 6;
  float* lb = lbuf[wid];
  int c = l & 15;
  bf16x8 wf[2][4];
  #pragma unroll
  for (int kt = 0; kt < 2; ++kt)
    #pragma unroll
    for (int nt = 0; nt < 4; ++nt) wf[kt][nt] = bfrag(W, kt, nt, l);
  float bias[4];
  #pragma unroll
  for (int nt = 0; nt < 4; ++nt) bias[nt] = has_bias ? b[nt*16 + c] : 0.0f;

  int ngrp = (N + 15) >> 4;
  for (int grp = blockIdx.x*4 + wid; grp < ngrp; grp += gridDim.x*4){
    int base = grp * 16;
    int ar = base + (l & 15);
    if (ar >= N) ar = N - 1;
    bf16x8 a0, a1;
    if (AF32){
      const float* row = (const float*)A + (size_t)ar * 64;
      a0 = afrag_f32(row + (l>>4)*8);
      a1 = afrag_f32(row + 32 + (l>>4)*8);
    } else {
      const u16* row = (const u16*)A + (size_t)ar * 64;
      a0 = *(const bf16x8*)(row + (l>>4)*8);
      a1 = *(const bf16x8*)(row + 32 + (l>>4)*8);
    }
    f32x4 acc[4];
    #pragma unroll
    for (int nt = 0; nt < 4; ++nt){
      f32x4 v; v[0]=bias[nt]; v[1]=bias[nt]; v[2]=bias[nt]; v[3]=bias[nt];
      v = MFMA(a0, wf[0][nt], v);
      v = MFMA(a1, wf[1][nt], v);
      acc[nt] = v;
    }
    dwrite(lb, acc, 1.0f, l);
    int nrows = N - base; if (nrows > 16) nrows = 16;
    store_rows2(lb, out, out, 1<<30, base, nrows, l);
  }
}

// ---------- MFMA finalize ----------
template<int OUTBF>
__global__ void __launch_bounds__(256) mfma_fin_k(
    const float* __restrict__ acc, const float* __restrict__ sdst,
    const float* __restrict__ W, const float* __restrict__ b,
    void* __restrict__ out, int N)
{
  __shared__ float lbuf[4][16*LDT];
  int l   = threadIdx.x & 63;
  int wid = threadIdx.x >> 6;
  float* lb = lbuf[wid];
  int r16 = l & 15, g = l >> 4;
  bf16x8 wf[2][4];
  #pragma unroll
  for (int kt = 0; kt < 2; ++kt)
    #pragma unroll
    for (int nt = 0; nt < 4; ++nt) wf[kt][nt] = bfrag(W, kt, nt, l);
  float bias[4];
  #pragma unroll
  for (int nt = 0; nt < 4; ++nt) bias[nt] = b[nt*16 + r16];

  int ngrp = (N + 15) >> 4;
  for (int grp = blockIdx.x*4 + wid; grp < ngrp; grp += gridDim.x*4){
    int base = grp * 16;
    int ar = base + r16; if (ar >= N) ar = N - 1;
    float s = sdst[ar];
    float inv = (s > 0.f) ? 1.0f / s : 0.0f;
    const float* row = acc + (size_t)ar * 64;
    bf16x8 a0 = afrag_f32s(row + g*8, inv);
    bf16x8 a1 = afrag_f32s(row + 32 + g*8, inv);
    f32x4 o[4];
    #pragma unroll
    for (int nt = 0; nt < 4; ++nt){
      f32x4 v; v[0]=bias[nt]; v[1]=bias[nt]; v[2]=bias[nt]; v[3]=bias[nt];
      v = MFMA(a0, wf[0][nt], v);
      v = MFMA(a1, wf[1][nt], v);
      o[nt] = v;
    }
    dwrite(lb, o, 0.2f, l);
    int nrows = N - base; if (nrows > 16) nrows = 16;
    if (OUTBF) store_rows2(lb, (u16*)out, (u16*)out, 1<<30, base, nrows, l);
    else       store_rows_f32(lb, (float*)out, base, nrows, l);
  }
}

// ---------- MFMA social finalize ----------
__global__ void __launch_bounds__(256) mfma_fin_social_k(
    const float* __restrict__ accS, const float* __restrict__ sdst,
    const u16* __restrict__ hI,
    const float* __restrict__ wS, const float* __restrict__ bS,
    const float* __restrict__ W2, const float* __restrict__ b2,
    float* __restrict__ out, int N)
{
  __shared__ float lbuf[4][16*LDT];
  int l   = threadIdx.x & 63;
  int wid = threadIdx.x >> 6;
  float* lb = lbuf[wid];
  int r16 = l & 15, g = l >> 4;
  bf16x8 wsf[2][4], w2f[4][4];
  #pragma unroll
  for (int kt = 0; kt < 2; ++kt)
    #pragma unroll
    for (int nt = 0; nt < 4; ++nt) wsf[kt][nt] = bfrag(wS, kt, nt, l);
  #pragma unroll
  for (int kt = 0; kt < 4; ++kt)
    #pragma unroll
    for (int nt = 0; nt < 4; ++nt) w2f[kt][nt] = bfrag(W2, kt, nt, l);
  float biasS[4], bias2[4];
  #pragma unroll
  for (int nt = 0; nt < 4; ++nt){ biasS[nt] = bS[nt*16 + r16]; bias2[nt] = b2[nt*16 + r16]; }

  int ngrp = (N + 15) >> 4;
  for (int grp = blockIdx.x*4 + wid; grp < ngrp; grp += gridDim.x*4){
    int base = grp * 16;
    int ar = base + r16; if (ar >= N) ar = N - 1;
    float s = sdst[ar];
    float inv = (s > 0.f) ? 1.0f / s : 0.0f;
    const float* row = accS + (size_t)ar * 64;
    bf16x8 a0 = afrag_f32s(row + g*8, inv);
    bf16x8 a1 = afrag_f32s(row + 32 + g*8, inv);
    f32x4 hs[4];
    #pragma unroll
    for (int nt = 0; nt < 4; ++nt){
      f32x4 v; v[0]=biasS[nt]; v[1]=biasS[nt]; v[2]=biasS[nt]; v[3]=biasS[nt];
      v = MFMA(a0, wsf[0][nt], v);
      v = MFMA(a1, wsf[1][nt], v);
      hs[nt] = v;
    }
    dwrite(lb, hs, 0.2f, l);
    bf16x8 h0 = afrag_lds(lb, 0, l);
    bf16x8 h1 = afrag_lds(lb, 1, l);
    const u16* hrow = hI + (size_t)ar * 64;
    bf16x8 i0 = *(const bf16x8*)(hrow + g*8);
    bf16x8 i1 = *(const bf16x8*)(hrow + 32 + g*8);
    f32x4 o[4];
    #pragma unroll
    for (int nt = 0; nt < 4; ++nt){
      f32x4 v; v[0]=bias2[nt]; v[1]=bias2[nt]; v[2]=bias2[nt]; v[3]=bias2[nt];
      v = MFMA(i0, w2f[0][nt], v);
      v = MFMA(i1, w2f[1][nt], v);
      v = MFMA(h0, w2f[2][nt], v);
      v = MFMA(h1, w2f[3][nt], v);
      o[nt] = v;
    }
    dwrite(lb, o, 0.2f, l);
    int nrows = N - base; if (nrows > 16) nrows = 16;
    store_rows_f32(lb, out, base, nrows, l);
  }
}

// ---------- CSR build: bucket pipeline ----------
__global__ void __launch_bounds__(256) hist2_k(const int* __restrict__ dstI, int E,
                                               int* __restrict__ H, int nb){
  __shared__ int h[512];
  for (int t = threadIdx.x; t < nb; t += 256) h[t] = 0;
  __syncthreads();
  int chunk = (E + PB - 1) / PB;
  int s = blockIdx.x * chunk;
  int e_end = s + chunk; if (e_end > E) e_end = E;
  for (int e = s + threadIdx.x; e < e_end; e += 256)
    atomicAdd(&h[dstI[e] >> 8], 1);
  __syncthreads();
  for (int t = threadIdx.x; t < nb; t += 256) H[t*PB + blockIdx.x] = h[t];
}
__global__ void __launch_bounds__(PB) totB_k(const int* __restrict__ H, int* __restrict__ tot){
  __shared__ int sh[PB];
  int b = blockIdx.x;
  sh[threadIdx.x] = H[b*PB + threadIdx.x];
  __syncthreads();
  for (int o = PB/2; o > 0; o >>= 1){
    if (threadIdx.x < o) sh[threadIdx.x] += sh[threadIdx.x + o];
    __syncthreads();
  }
  if (threadIdx.x == 0) tot[b] = sh[0];
}
__global__ void __launch_bounds__(512) scanB_k(const int* __restrict__ tot,
                                               int* __restrict__ baseB, int nb){
  __shared__ int sh[512];
  int v = (threadIdx.x < nb) ? tot[threadIdx.x] : 0;
  sh[threadIdx.x] = v;
  __syncthreads();
  for (int o = 1; o < 512; o <<= 1){
    int t = (threadIdx.x >= o) ? sh[threadIdx.x - o] : 0;
    __syncthreads();
    sh[threadIdx.x] += t;
    __syncthreads();
  }
  if (threadIdx.x < nb) baseB[threadIdx.x] = sh[threadIdx.x] - v;
  if (threadIdx.x == nb - 1) baseB[nb] = sh[threadIdx.x];
}
__global__ void __launch_bounds__(PB) offB_k(int* __restrict__ H, const int* __restrict__ baseB){
  __shared__ int sh[PB];
  int b = blockIdx.x;
  int v = H[b*PB + threadIdx.x];
  sh[threadIdx.x] = v;
  __syncthreads();
  for (int o = 1; o < PB; o <<= 1){
    int t = (threadIdx.x >= o) ? sh[threadIdx.x - o] : 0;
    __syncthreads();
    sh[threadIdx.x] += t;
    __syncthreads();
  }
  H[b*PB + threadIdx.x] = baseB[b] + sh[threadIdx.x] - v;
}
__global__ void __launch_bounds__(256) part_k(
    const int* __restrict__ keyI, const int* __restrict__ ratI, int kmul,
    const int* __restrict__ dstI, const int* __restrict__ H, int nb,
    long long* __restrict__ kd2, int E){
  __shared__ int cur[512];
  for (int t = threadIdx.x; t < nb; t += 256) cur[t] = H[t*PB + blockIdx.x];
  __syncthreads();
  int chunk = (E + PB - 1) / PB;
  int s = blockIdx.x * chunk;
  int e_end = s + chunk; if (e_end > E) e_end = E;
  for (int e = s + threadIdx.x; e < e_end; e += 256){
    int d = dstI[e];
    int key = keyI[e]*kmul + (ratI ? ratI[e] : 0);
    int pos = atomicAdd(&cur[d >> 8], 1);
    long long v = ((long long)d << 32) | (unsigned)key;
    __builtin_nontemporal_store(v, kd2 + pos);
  }
}
__global__ void __launch_bounds__(256) bsort_k(
    const long long* __restrict__ kd2, const int* __restrict__ baseB,
    int N, long long* __restrict__ kd, int* __restrict__ rowptr, int E){
  __shared__ int cnt[RANGE];
  __shared__ int off[RANGE];
  int b = blockIdx.x;
  int lo = baseB[b], hi = baseB[b+1];
  cnt[threadIdx.x] = 0;
  __syncthreads();
  for (int k = lo + (int)threadIdx.x; k < hi; k += 256){
    int d = (int)(kd2[k] >> 32);
    atomicAdd(&cnt[d & 255], 1);
  }
  __syncthreads();
  int v = cnt[threadIdx.x];
  off[threadIdx.x] = v;
  __syncthreads();
  for (int o = 1; o < RANGE; o <<= 1){
    int t = (threadIdx.x >= o) ? off[threadIdx.x - o] : 0;
    __syncthreads();
    off[threadIdx.x] += t;
    __syncthreads();
  }
  int excl = off[threadIdx.x] - v;
  int d0 = b*RANGE + (int)threadIdx.x;
  if (d0 < N) rowptr[d0] = lo + excl;
  if (b == (int)gridDim.x - 1 && threadIdx.x == 0) rowptr[N] = E;
  __syncthreads();
  cnt[threadIdx.x] = lo + excl;
  __syncthreads();
  for (int k = lo + (int)threadIdx.x; k < hi; k += 256){
    long long v2 = kd2[k];
    int d = (int)(v2 >> 32);
    int pos = atomicAdd(&cnt[d & 255], 1);
    kd[pos] = v2;
  }
}

// ---------- fused MFMA score over sorted edges ----------
template<int CY>
__global__ void __launch_bounds__(256) fscore_k(
    const int2* __restrict__ kd,
    const u16* __restrict__ Xlo, const u16* __restrict__ Xhi, int ndout,
    int klo, int nk,
    const u16* __restrict__ Dtab,
    const float* __restrict__ Wy,
    const float* __restrict__ W2, const float* __restrict__ b2,
    const float* __restrict__ w3, const float* __restrict__ b3,
    float* __restrict__ esc, int E)
{
  __shared__ float lbuf[CY ? 4*16*LDT : 4];
  int l   = threadIdx.x & 63;
  int wid = threadIdx.x >> 6;
  int r16 = l & 15, g = l >> 4;
  float* lb = lbuf + (CY ? wid*16*LDT : 0);
  bf16x8 wyf[2][4], w2f[2][4];
  if (CY){
    #pragma unroll
    for (int kt = 0; kt < 2; ++kt)
      #pragma unroll
      for (int nt = 0; nt < 4; ++nt) wyf[kt][nt] = bfrag(Wy, kt, nt, l);
  }
  #pragma unroll
  for (int kt = 0; kt < 2; ++kt)
    #pragma unroll
    for (int nt = 0; nt < 4; ++nt) w2f[kt][nt] = bfrag(W2, kt, nt, l);
  f32x4 b2v[4]; float w3v[4];
  #pragma unroll
  for (int nt = 0; nt < 4; ++nt){
    float bv = b2[nt*16 + r16];
    f32x4 t; t[0]=bv; t[1]=bv; t[2]=bv; t[3]=bv;
    b2v[nt] = t;
    w3v[nt] = w3[nt*16 + r16];
  }
  float b3v = b3[0];

  int ngrp = (E + 15) >> 4;
  for (int grp = blockIdx.x*4 + wid; grp < ngrp; grp += gridDim.x*4){
    int pos = grp*16 + r16;
    int pc  = pos < E ? pos : E - 1;
    int2 kde = kd[pc];
    int j   = kde.x - klo;
    bool inr = (pos < E) && ((unsigned)j < (unsigned)nk);
    unsigned long long bal = __ballot(inr ? 1 : 0);
    uint4 xa = {0,0,0,0}, xb = xa, da = xa, db = xa;
    if (inr){
      const u16* xr = (j < ndout) ? Xlo + (size_t)j * 64 : Xhi + (size_t)(j - ndout) * 64;
      xa = *(const uint4*)(xr + g*8);
      xb = *(const uint4*)(xr + 32 + g*8);
      const u16* dr = Dtab + (size_t)kde.y * 64;
      da = *(const uint4*)(dr + g*8);
      db = *(const uint4*)(dr + 32 + g*8);
    }
    bf16x8 p0, p1;
    float dfa[8], dfb[8];
    cvt8(da, dfa); cvt8(db, dfb);
    if (CY){
      bf16x8 a0 = *reinterpret_cast<const bf16x8*>(&xa);
      bf16x8 a1 = *reinterpret_cast<const bf16x8*>(&xb);
      f32x4 y[4];
      #pragma unroll
      for (int nt = 0; nt < 4; ++nt){
        f32x4 z; z[0]=0.f; z[1]=0.f; z[2]=0.f; z[3]=0.f;
        z = MFMA(a0, wyf[0][nt], z);
        z = MFMA(a1, wyf[1][nt], z);
        y[nt] = z;
      }
      #pragma unroll
      for (int nt = 0; nt < 4; ++nt)
        #pragma unroll
        for (int rg = 0; rg < 4; ++rg)
          lb[(4*g + rg)*LDT + nt*16 + r16] = y[nt][rg];
      const float* pr = lb + r16*LDT;
      float4 f0 = *(const float4*)(pr + g*8);
      float4 f1 = *(const float4*)(pr + g*8 + 4);
      float4 f2 = *(const float4*)(pr + 32 + g*8);
      float4 f3 = *(const float4*)(pr + 36 + g*8);
      float q0[8] = {f0.x,f0.y,f0.z,f0.w,f1.x,f1.y,f1.z,f1.w};
      float q1[8] = {f2.x,f2.y,f2.z,f2.w,f3.x,f3.y,f3.z,f3.w};
      #pragma unroll
      for (int u = 0; u < 8; ++u){
        p0[u] = (short)f2bf(fmaxf(q0[u] + dfa[u], 0.0f));
        p1[u] = (short)f2bf(fmaxf(q1[u] + dfb[u], 0.0f));
      }
    } else {
      float xfa[8], xfb[8];
      cvt8(xa, xfa); cvt8(xb, xfb);
      #pragma unroll
      for (int u = 0; u < 8; ++u){
        p0[u] = (short)f2bf(fmaxf(xfa[u] + dfa[u], 0.0f));
        p1[u] = (short)f2bf(fmaxf(xfb[u] + dfb[u], 0.0f));
      }
    }
    f32x4 o[4];
    #pragma unroll
    for (int nt = 0; nt < 4; ++nt){
      f32x4 v = b2v[nt];
      v = MFMA(p0, w2f[0][nt], v);
      v = MFMA(p1, w2f[1][nt], v);
      o[nt] = v;
    }
    float part[4] = {0.f, 0.f, 0.f, 0.f};
    #pragma unroll
    for (int nt = 0; nt < 4; ++nt)
      #pragma unroll
      for (int rg = 0; rg < 4; ++rg)
        part[rg] += fmaxf(o[nt][rg], 0.0f) * w3v[nt];
    #pragma unroll
    for (int m = 1; m < 16; m <<= 1){
      #pragma unroll
      for (int rg = 0; rg < 4; ++rg) part[rg] += __shfl_xor(part[rg], m);
    }
    if (r16 < 4){
      int eidx = 4*g + r16;
      int p2 = grp*16 + eidx;
      if (p2 < E && ((bal >> eidx) & 1))
        esc[p2] = __expf(part[r16] + b3v);
    }
  }
}

// ---------- 8-lane-per-dst pipelined segmented accumulate + denominator ----------
template<int FIRST>
__global__ void __launch_bounds__(256) agg8_k(
    const int* __restrict__ rowptr, const int2* __restrict__ kd,
    const float* __restrict__ esc,
    const u16* __restrict__ Xlo, const u16* __restrict__ Xhi, int ndout,
    int klo, int nk,
    float* __restrict__ acc, float* __restrict__ sdst, int N)
{
  int t = blockIdx.x*256 + threadIdx.x;
  int d = t >> 3, q = t & 7;
  if (d >= N) return;
  float a[8];
  float* ar = acc + (size_t)d * 64 + q*8;
  float s;
  if (FIRST){
    #pragma unroll
    for (int u = 0; u < 8; ++u) a[u] = 0.0f;
    s = 0.0f;
  } else {
    float4 v0 = *(const float4*)(ar);
    float4 v1 = *(const float4*)(ar + 4);
    a[0]=v0.x; a[1]=v0.y; a[2]=v0.z; a[3]=v0.w;
    a[4]=v1.x; a[5]=v1.y; a[6]=v1.z; a[7]=v1.w;
    s = sdst[d];
  }
  int k0 = rowptr[d], k1 = rowptr[d+1];
  auto xrow = [&](int key)->const u16*{
    return ((key < ndout) ? Xlo + (size_t)key * 64
                          : Xhi + (size_t)(key - ndout) * 64) + q*8;
  };
  if (k0 < k1){
    int key = kd[k0].x - klo;
    bool ok = (unsigned)key < (unsigned)nk;
    float w = ok ? esc[k0] : 0.0f;
    uint4 x = {0,0,0,0};
    if (ok) x = *(const uint4*)xrow(key);
    for (int k = k0 + 1; k < k1; ++k){
      int key2 = kd[k].x - klo;               // prefetch next edge
      bool ok2 = (unsigned)key2 < (unsigned)nk;
      float w2 = ok2 ? esc[k] : 0.0f;
      uint4 x2 = {0,0,0,0};
      if (ok2) x2 = *(const uint4*)xrow(key2);
      s += w;
      float f[8]; cvt8(x, f);
      #pragma unroll
      for (int u = 0; u < 8; ++u) a[u] = fmaf(w, f[u], a[u]);
      x = x2; w = w2;
    }
    s += w;
    float f[8]; cvt8(x, f);
    #pragma unroll
    for (int u = 0; u < 8; ++u) a[u] = fmaf(w, f[u], a[u]);
  }
  *(float4*)(ar)     = make_float4(a[0], a[1], a[2], a[3]);
  *(float4*)(ar + 4) = make_float4(a[4], a[5], a[6], a[7]);
  if (q == 0) sdst[d] = s;
}

extern "C" void kernel_launch(void* const* d_in, const int* in_sizes, int n_in,
                              void* d_out, int out_size, void* d_ws, size_t ws_size,
                              hipStream_t stream) {
  (void)in_sizes; (void)n_in; (void)out_size;
  const float* user_emb   = (const float*)d_in[0];
  const float* item_emb   = (const float*)d_in[1];
  const float* rating_emb = (const float*)d_in[2];
  const float *gv_w1=(const float*)d_in[3],  *gv_b1=(const float*)d_in[4];
  const float *gv_w2=(const float*)d_in[5],  *gv_b2=(const float*)d_in[6];
  const float *aI_w1=(const float*)d_in[7],  *aI_b1=(const float*)d_in[8];
  const float *aI_w2=(const float*)d_in[9],  *aI_b2=(const float*)d_in[10];
  const float *aI_w3=(const float*)d_in[11], *aI_b3=(const float*)d_in[12];
  const float *wI_w =(const float*)d_in[13], *wI_b =(const float*)d_in[14];
  const float *aS_w1=(const float*)d_in[15], *aS_b1=(const float*)d_in[16];
  const float *aS_w2=(const float*)d_in[17], *aS_b2=(const float*)d_in[18];
  const float *aS_w3=(const float*)d_in[19], *aS_b3=(const float*)d_in[20];
  const float *wS_w =(const float*)d_in[21], *wS_b =(const float*)d_in[22];
  const float *W2_w =(const float*)d_in[23], *W2_b =(const float*)d_in[24];
  const float *gu_w1=(const float*)d_in[25], *gu_b1=(const float*)d_in[26];
  const float *gu_w2=(const float*)d_in[27], *gu_b2=(const float*)d_in[28];
  const float *aU_w1=(const float*)d_in[29], *aU_b1=(const float*)d_in[30];
  const float *aU_w2=(const float*)d_in[31], *aU_b2=(const float*)d_in[32];
  const float *aU_w3=(const float*)d_in[33], *aU_b3=(const float*)d_in[34];
  const float *wU_w =(const float*)d_in[35], *wU_b =(const float*)d_in[36];
  const int* user_e    = (const int*)d_in[37];
  const int* item_e    = (const int*)d_in[38];
  const int* rating_e  = (const int*)d_in[39];
  const int* trust_e   = (const int*)d_in[40];
  const int* trustee_e = (const int*)d_in[41];
  float* dout = (float*)d_out;

  char* base = (char*)d_ws;
  size_t cur = 0;
  auto alloc = [&](size_t bytes)->char*{
    char* p = base + cur; cur += (bytes + 255) & ~(size_t)255; return p;
  };
  u16*   hI     = (u16*)  alloc((size_t)U_N * 64 * 2);
  float* esc    = (float*)alloc((size_t)EUI_E * 4);
  float* sdst   = (float*)alloc((size_t)U_N * 4);
  int*   rowptr = (int*)  alloc((size_t)(U_N + 1) * 4);
  int2*  kd     = (int2*) alloc((size_t)EUI_E * 8);
  int*   H      = (int*)  alloc((size_t)512 * PB * 4);
  int*   tot    = (int*)  alloc(512 * 4);
  int*   baseB  = (int*)  alloc(513 * 4);
  float* acc    = (float*)alloc((size_t)U_N * 64 * 4);   // 25.6 MB
  long long* kd2 = (long long*)acc;                      // alias (CSR build time)
  size_t fixed_end = cur;
  if (ws_size < fixed_end + 13100000) return;
  u16* tabD = (u16*)(base + fixed_end);
  u16* tabX = (u16*)(base + fixed_end + 6500352);
  size_t arena = ws_size - fixed_end;
  u16* Xdout = (u16*)d_out;

  auto cdiv = [](int a, int b){ return (a + b - 1) / b; };
  auto buildCSR = [&](const int* keyI, const int* ratI, int kmul,
                      const int* dstIdx, int E, int N){
    int nb = cdiv(N, RANGE);
    hist2_k<<<PB, 256, 0, stream>>>(dstIdx, E, H, nb);
    totB_k<<<nb, PB, 0, stream>>>(H, tot);
    scanB_k<<<1, 512, 0, stream>>>(tot, baseB, nb);
    offB_k<<<nb, PB, 0, stream>>>(H, baseB);
    part_k<<<PB, 256, 0, stream>>>(keyI, ratI, kmul, dstIdx, H, nb, kd2, E);
    bsort_k<<<nb, 256, 0, stream>>>(kd2, baseB, N, (long long*)kd, rowptr, E);
  };
  auto gCap = [&](int groups){ int g = cdiv(groups, 4); return g > 1536 ? 1536 : g; };

  // ============ Phase 1: ItemAgg (dst = user) ============
  {
    buildCSR(item_e, rating_e, 5, user_e, EUI_E, U_N);
    mfma_lin_k<1><<<gCap(cdiv(U_N,16)), 256, 0, stream>>>(user_emb, aI_w1 + 64*64, aI_b1, 1, tabD, U_N);
    const int NK = 250000;
    mfma_pair_k<<<gCap(cdiv(NK,16)), 256, 0, stream>>>(item_emb, rating_emb,
        gv_w1, gv_b1, gv_w2, gv_b2, 0.01f, 0, NK, Xdout, Xdout, 1<<30);
    fscore_k<1><<<gCap(cdiv(EUI_E,16)), 256, 0, stream>>>(kd,
        Xdout, Xdout, 1<<30, 0, NK, tabD, aI_w1, aI_w2, aI_b2, aI_w3, aI_b3, esc, EUI_E);
    agg8_k<1><<<cdiv(U_N*8,256), 256, 0, stream>>>(rowptr, kd, esc,
        Xdout, Xdout, 1<<30, 0, NK, acc, sdst, U_N);
    mfma_fin_k<1><<<gCap(cdiv(U_N,16)), 256, 0, stream>>>(acc, sdst, wI_w, wI_b, hI, U_N);
  }

  // ============ Phase 2: UserAgg (dst = item) ============
  {
    buildCSR(user_e, rating_e, 5, item_e, EUI_E, I_N);
    mfma_lin_k<1><<<gCap(cdiv(I_N,16)), 256, 0, stream>>>(item_emb, aU_w1 + 64*64, aU_b1, 1, tabD, I_N);
    bool single = arena >= 33000000;
    int CP = single ? 500000 : 250000;
    int ND = single ? DOUT_ROWS : (1<<30);
    for (int klo = 0; klo < 500000; klo += CP){
      mfma_pair_k<<<gCap(cdiv(CP,16)), 256, 0, stream>>>(user_emb, rating_emb,
          gu_w1, gu_b1, gu_w2, gu_b2, 0.0f, klo, klo + CP, Xdout, tabX, ND);
      fscore_k<1><<<gCap(cdiv(EUI_E,16)), 256, 0, stream>>>(kd,
          Xdout, tabX, ND, klo, CP, tabD, aU_w1, aU_w2, aU_b2, aU_w3, aU_b3, esc, EUI_E);
      if (klo == 0)
        agg8_k<1><<<cdiv(I_N*8,256), 256, 0, stream>>>(rowptr, kd, esc,
            Xdout, tabX, ND, klo, CP, acc, sdst, I_N);
      else
        agg8_k<0><<<cdiv(I_N*8,256), 256, 0, stream>>>(rowptr, kd, esc,
            Xdout, tabX, ND, klo, CP, acc, sdst, I_N);
    }
    mfma_fin_k<0><<<gCap(cdiv(I_N,16)), 256, 0, stream>>>(acc, sdst, wU_w, wU_b,
        dout + (size_t)U_N * 64, I_N);
  }

  // ============ Phase 3: SocialAgg (dst = trustee) ============
  {
    buildCSR(trust_e, (const int*)nullptr, 1, trustee_e, EUU_E, U_N);
    u16* SD = Xdout;
    mfma_lin_k<1><<<gCap(cdiv(U_N,16)), 256, 0, stream>>>(user_emb, aS_w1, aS_b1, 0, tabD, U_N); // SS
    mfma_lin_k<0><<<gCap(cdiv(U_N,16)), 256, 0, stream>>>(hI, aS_w1 + 64*64, aS_b1, 1, SD, U_N); // SD
    fscore_k<0><<<gCap(cdiv(EUU_E,16)), 256, 0, stream>>>(kd,
        tabD, tabD, 1<<30, 0, U_N, SD, (const float*)nullptr,
        aS_w2, aS_b2, aS_w3, aS_b3, esc, EUU_E);
    agg8_k<1><<<cdiv(U_N*8,256), 256, 0, stream>>>(rowptr, kd, esc,
        hI, hI, 1<<30, 0, U_N, acc, sdst, U_N);
    mfma_fin_social_k<<<gCap(cdiv(U_N,16)), 256, 0, stream>>>(acc, sdst, hI,
        wS_w, wS_b, W2_w, W2_b, dout, U_N);
  }
}